// Round 1
// baseline (3103.656 us; speedup 1.0000x reference)
//
#include <hip/hip_runtime.h>
#include <cstddef>
#include <cstdint>

#define DEVI __device__ __forceinline__

namespace {

constexpr int T_N = 128;
constexpr int B_N = 256;
constexpr int DH  = 512;

DEVI float sigmoidf_(float v) { return 1.f / (1.f + expf(-v)); }
DEVI float softplusf_(float v) { return fmaxf(v, 0.f) + log1pf(expf(-fabsf(v))); }

// ---- A-operand virtual addressing ------------------------------------
// AMODE 0: A0 row-major (M x Ktot)
// AMODE 2: rev_a: m=(b<<7|t) -> a[((127-t)<<8)|b], ld 512
// AMODE 3: hp:    m=(b<<7|t) -> h[(t<<8)|b], ld 512
// AMODE 4: dec:   k<128: zk[m*128+k]; else hp col (k-128)
// AMODE 5: x batch-half: m=(t<<7|bb) -> x[(t*256+bb+boff)*64+k]
// AMODE 6: rev [y,h] batch-half: mr=(127-t)*256+bb+boff; k<64: y; else h
template <int AMODE>
DEVI const float* a_src(const float* __restrict__ A0, const float* __restrict__ A1,
                        int m, int k, int lda, int boff) {
  if constexpr (AMODE == 0) {
    return A0 + (size_t)m * lda + k;
  } else if constexpr (AMODE == 2) {
    int b = m >> 7, t = m & 127;
    return A0 + ((size_t)(((127 - t) << 8) | b)) * 512 + k;
  } else if constexpr (AMODE == 3) {
    return A0 + ((size_t)(((m & 127) << 8) | (m >> 7))) * 512 + k;
  } else if constexpr (AMODE == 4) {
    if (k < 128) return A0 + (size_t)m * 128 + k;
    return A1 + ((size_t)(((m & 127) << 8) | (m >> 7))) * 512 + (k - 128);
  } else if constexpr (AMODE == 5) {
    int t = m >> 7, b = (m & 127) + boff;
    return A0 + ((size_t)(t * 256 + b)) * 64 + k;
  } else {  // 6
    int t = m >> 7, b = (m & 127) + boff;
    int mr = (127 - t) * 256 + b;
    if (k < 64) return A0 + (size_t)mr * 64 + k;
    return A1 + (size_t)mr * 512 + (k - 64);
  }
}

// ACT: 1 relu, 4 qrnn (tanh n<512 else sigmoid), 9 pair (sigmoid | softplus)
template <int ACT>
DEVI float act_apply(float v, int n) {
  if constexpr (ACT == 0) return v;
  else if constexpr (ACT == 1) return fmaxf(v, 0.f);
  else if constexpr (ACT == 2) return sigmoidf_(v);
  else if constexpr (ACT == 3) return softplusf_(v);
  else return (n < DH) ? tanhf(v) : sigmoidf_(v);  // ACT 4
}

// C[m,n] = act( sum_k A[m,k] * W[n,k] + bias[n] ); 128x128 tile, BK=16,
// 256 threads, 8x8 micro-tile per thread. ACT==9: paired heads, W/W2 split
// at Nh=N/2, outputs to C (sigmoid) and C2 (softplus).
template <int AMODE, int ACT>
__global__ __launch_bounds__(256)
void gemm_k(const float* __restrict__ A0, const float* __restrict__ A1,
            const float* __restrict__ W, const float* __restrict__ bias,
            const float* __restrict__ W2, const float* __restrict__ bias2,
            float* __restrict__ C, float* __restrict__ C2,
            int N, int Ktot, int boff) {
  __shared__ float As[16][132];   // [k][m], stride 132 -> write conflicts are 2-way (free)
  __shared__ float Bs[16][132];   // [k][n]
  const int tid = threadIdx.x;
  const int m0 = blockIdx.x * 128;
  const int n0 = blockIdx.y * 128;
  const int lr = tid >> 1;         // tile row 0..127
  const int lc = (tid & 1) * 8;    // k-chunk 0 or 8
  const int tx = tid & 15;
  const int ty = tid >> 4;
  const int Nh = N >> 1;

  float acc[8][8];
#pragma unroll
  for (int i = 0; i < 8; ++i)
#pragma unroll
    for (int j = 0; j < 8; ++j) acc[i][j] = 0.f;

  for (int kt = 0; kt < Ktot; kt += 16) {
    // global fetch (8 A + 8 B floats per thread); k-chunks of 8 never straddle
    // the 64/128 concat boundaries (all multiples of 8).
    const float* ap = a_src<AMODE>(A0, A1, m0 + lr, kt + lc, Ktot, boff);
    const float4 a0 = *(const float4*)ap;
    const float4 a1 = *(const float4*)(ap + 4);
    float4 b0 = make_float4(0.f, 0.f, 0.f, 0.f), b1 = b0;
    const int wr = n0 + lr;
    if (wr < N) {
      const float* bp;
      if constexpr (ACT == 9) {
        bp = (wr < Nh) ? (W + (size_t)wr * Ktot + kt + lc)
                       : (W2 + (size_t)(wr - Nh) * Ktot + kt + lc);
      } else {
        bp = W + (size_t)wr * Ktot + kt + lc;
      }
      b0 = *(const float4*)bp;
      b1 = *(const float4*)(bp + 4);
    }
    __syncthreads();               // previous iter's compute done
    As[lc + 0][lr] = a0.x; As[lc + 1][lr] = a0.y;
    As[lc + 2][lr] = a0.z; As[lc + 3][lr] = a0.w;
    As[lc + 4][lr] = a1.x; As[lc + 5][lr] = a1.y;
    As[lc + 6][lr] = a1.z; As[lc + 7][lr] = a1.w;
    Bs[lc + 0][lr] = b0.x; Bs[lc + 1][lr] = b0.y;
    Bs[lc + 2][lr] = b0.z; Bs[lc + 3][lr] = b0.w;
    Bs[lc + 4][lr] = b1.x; Bs[lc + 5][lr] = b1.y;
    Bs[lc + 6][lr] = b1.z; Bs[lc + 7][lr] = b1.w;
    __syncthreads();
#pragma unroll
    for (int kk = 0; kk < 16; ++kk) {
      const float4 av0 = *(const float4*)&As[kk][ty * 8];
      const float4 av1 = *(const float4*)&As[kk][ty * 8 + 4];
      const float4 bv0 = *(const float4*)&Bs[kk][tx * 8];
      const float4 bv1 = *(const float4*)&Bs[kk][tx * 8 + 4];
      const float am[8] = {av0.x, av0.y, av0.z, av0.w, av1.x, av1.y, av1.z, av1.w};
      const float bm[8] = {bv0.x, bv0.y, bv0.z, bv0.w, bv1.x, bv1.y, bv1.z, bv1.w};
#pragma unroll
      for (int i = 0; i < 8; ++i)
#pragma unroll
        for (int j = 0; j < 8; ++j) acc[i][j] = fmaf(am[i], bm[j], acc[i][j]);
    }
  }

  const int nb = n0 + tx * 8;
  if (nb >= N) return;            // N=64/128 tails: whole 8-chunk in/out (N mult of 64)
  if constexpr (ACT == 9) {
    const bool second = nb >= Nh;
    const float* bptr = second ? bias2 : bias;
    float* cptr = second ? C2 : C;
    const int nloc = second ? nb - Nh : nb;
    float bv[8];
#pragma unroll
    for (int j = 0; j < 8; ++j) bv[j] = bptr[nloc + j];
#pragma unroll
    for (int i = 0; i < 8; ++i) {
      const int m = m0 + ty * 8 + i;
      float r[8];
#pragma unroll
      for (int j = 0; j < 8; ++j) {
        const float v = acc[i][j] + bv[j];
        r[j] = second ? softplusf_(v) : sigmoidf_(v);
      }
      *(float4*)&cptr[(size_t)m * Nh + nloc]     = make_float4(r[0], r[1], r[2], r[3]);
      *(float4*)&cptr[(size_t)m * Nh + nloc + 4] = make_float4(r[4], r[5], r[6], r[7]);
    }
  } else {
    float bv[8];
#pragma unroll
    for (int j = 0; j < 8; ++j) bv[j] = bias[nb + j];
#pragma unroll
    for (int i = 0; i < 8; ++i) {
      const int m = m0 + ty * 8 + i;
      float r[8];
#pragma unroll
      for (int j = 0; j < 8; ++j) r[j] = act_apply<ACT>(acc[i][j] + bv[j], nb + j);
      *(float4*)&C[(size_t)m * N + nb]     = make_float4(r[0], r[1], r[2], r[3]);
      *(float4*)&C[(size_t)m * N + nb + 4] = make_float4(r[4], r[5], r[6], r[7]);
    }
  }
}

// Forget-mult scan over one batch-half. Y: (T,128,1536) compact, gates
// pre-activated (tanh Z | sigm F | sigm O). H: full (T,256,512) layout.
__global__ __launch_bounds__(256)
void scan_k(const float* __restrict__ Y, float* __restrict__ H, int boff) {
  const int idx = blockIdx.x * 256 + threadIdx.x;  // [0, 65536)
  const int bb = idx >> 9;
  const int hh = idx & 511;
  float c = 0.f;                                   // h0 = 0
  const float* p = Y + (size_t)bb * 1536 + hh;
  float* q = H + ((size_t)(bb + boff)) * 512 + hh;
#pragma unroll 4
  for (int t = 0; t < 128; ++t) {
    const float z = p[0], f = p[512], o = p[1024];
    c = f * z + (1.f - f) * c;
    q[0] = o * c;
    p += 128 * 1536;
    q += 256 * 512;
  }
}

__global__ __launch_bounds__(256)
void z0_k(const float* __restrict__ mean, const float* __restrict__ sd,
          const float* __restrict__ eps, float* __restrict__ z) {
  const int i = blockIdx.x * 256 + threadIdx.x;
  const float4 m = ((const float4*)mean)[i];
  const float4 s = ((const float4*)sd)[i];
  const float4 e = ((const float4*)eps)[i];
  ((float4*)z)[i] = make_float4(m.x + s.x * e.x, m.y + s.y * e.y,
                                m.z + s.z * e.z, m.w + s.w * e.w);
}

// Per-k flow constants: u_hat (K,128) and wu[k] = dot(w_k, u_hat_k).
__global__ __launch_bounds__(64)
void flow_pre_k(const float* __restrict__ u, const float* __restrict__ w,
                float* __restrict__ uhat, float* __restrict__ wu) {
  const int k = blockIdx.x, l = threadIdx.x;
  const float w0 = w[k * 128 + l], w1 = w[k * 128 + 64 + l];
  const float u0 = u[k * 128 + l], u1 = u[k * 128 + 64 + l];
  float nrm = w0 * w0 + w1 * w1;
  float udw = u0 * w0 + u1 * w1;
#pragma unroll
  for (int o = 32; o; o >>= 1) { nrm += __shfl_xor(nrm, o); udw += __shfl_xor(udw, o); }
  const float inv = 1.f / sqrtf(nrm);
  const float coef = (softplusf_(udw) - 1.f) - udw;   // m(udw) - udw
  const float uh0 = coef * (w0 * inv) + u0;
  const float uh1 = coef * (w1 * inv) + u1;
  uhat[k * 128 + l] = uh0;
  uhat[k * 128 + 64 + l] = uh1;
  float dwu = w0 * uh0 + w1 * uh1;
#pragma unroll
  for (int o = 32; o; o >>= 1) dwu += __shfl_xor(dwu, o);
  if (l == 0) wu[k] = dwu;
}

// One wave per (b,t) row; z row (128) in 2 regs/lane; 16 sequential flow steps.
__global__ __launch_bounds__(256)
void flow_k(float* __restrict__ z, const float* __restrict__ w,
            const float* __restrict__ b, const float* __restrict__ uhat,
            const float* __restrict__ wu, float* __restrict__ sldj) {
  const int row = blockIdx.x * 4 + (threadIdx.x >> 6);
  const int l = threadIdx.x & 63;
  float* zp = z + (size_t)row * 128;
  float z0 = zp[l], z1 = zp[64 + l];
  float sl = 0.f;
#pragma unroll
  for (int k = 0; k < 16; ++k) {
    const float w0 = w[k * 128 + l], w1 = w[k * 128 + 64 + l];
    float s = z0 * w0 + z1 * w1;
#pragma unroll
    for (int o = 32; o; o >>= 1) s += __shfl_xor(s, o);
    const float t = tanhf(s + b[k]);
    z0 += uhat[k * 128 + l] * t;
    z1 += uhat[k * 128 + 64 + l] * t;
    const float psi = (1.f - t * t) * wu[k];
    sl -= logf(fabsf(psi + 1.f) + 1e-8f);
  }
  zp[l] = z0;
  zp[64 + l] = z1;
  if (l == 0) sldj[row] = sl;
}

}  // namespace

extern "C" void kernel_launch(void* const* d_in, const int* in_sizes, int n_in,
                              void* d_out, int out_size, void* d_ws, size_t ws_size,
                              hipStream_t stream) {
  const float* x           = (const float*)d_in[0];
  const float* y           = (const float*)d_in[1];
  const float* eps         = (const float*)d_in[2];
  const float* hs_W        = (const float*)d_in[3];
  const float* hs_b        = (const float*)d_in[4];
  const float* q_W         = (const float*)d_in[5];
  const float* q_b         = (const float*)d_in[6];
  const float* enc_phi_W   = (const float*)d_in[7];
  const float* enc_phi_b   = (const float*)d_in[8];
  const float* enc_mean_W  = (const float*)d_in[9];
  const float* enc_mean_b  = (const float*)d_in[10];
  const float* enc_std_W   = (const float*)d_in[11];
  const float* enc_std_b   = (const float*)d_in[12];
  const float* prior_phi_W = (const float*)d_in[13];
  const float* prior_phi_b = (const float*)d_in[14];
  const float* prior_mean_W= (const float*)d_in[15];
  const float* prior_mean_b= (const float*)d_in[16];
  const float* prior_std_W = (const float*)d_in[17];
  const float* prior_std_b = (const float*)d_in[18];
  const float* dec_W1      = (const float*)d_in[19];
  const float* dec_b1      = (const float*)d_in[20];
  const float* dec_W2      = (const float*)d_in[21];
  const float* dec_b2      = (const float*)d_in[22];
  const float* dec_mean_W  = (const float*)d_in[23];
  const float* dec_mean_b  = (const float*)d_in[24];
  const float* dec_std_W   = (const float*)d_in[25];
  const float* dec_std_b   = (const float*)d_in[26];
  const float* pnf_u       = (const float*)d_in[27];
  const float* pnf_w       = (const float*)d_in[28];
  const float* pnf_b       = (const float*)d_in[29];

  float* out = (float*)d_out;            // fp32 outputs, concatenated:
  float* dec_mean  = out;                //  (256,128,64)
  float* dec_std   = out + 2097152;      //  (256,128,64)
  float* enc_mean  = out + 4194304;      //  (256,128,128)
  float* enc_std   = out + 8388608;
  float* prior_mean= out + 12582912;
  float* prior_std = out + 16777216;
  float* zk        = out + 20971520;     //  (256,128,128)
  float* sldj      = out + 25165824;     //  (256,128)

  // ws: Ybuf 25.17M | h 16.78M | a/e2 16.78M | uhat 2048 | wu 16  => 224 MiB
  float* ws   = (float*)d_ws;
  float* Ybuf = ws;                   // (T,128,1536) per batch-half; later e1/p1/d1
  float* hbuf = ws + 25165824;        // h (T,256,512), live to decoder
  float* abuf = ws + 41943040;        // a (T,256,512); later e2/p2/d2
  float* uhat = ws + 58720256;
  float* wu   = ws + 58722304;
  float* e1 = Ybuf;
  float* e2 = abuf;

  const dim3 blk(256);

  // ---- QRNN chain (recurrence independent per b -> two batch halves) ----
  for (int half = 0; half < 2; ++half) {
    const int boff = half * 128;
    gemm_k<5, 4><<<dim3(128, 12), blk, 0, stream>>>(x, nullptr, hs_W, hs_b,
        nullptr, nullptr, Ybuf, nullptr, 1536, 64, boff);
    scan_k<<<256, blk, 0, stream>>>(Ybuf, hbuf, boff);
    gemm_k<6, 4><<<dim3(128, 12), blk, 0, stream>>>(y, hbuf, q_W, q_b,
        nullptr, nullptr, Ybuf, nullptr, 1536, 576, boff);
    scan_k<<<256, blk, 0, stream>>>(Ybuf, abuf, boff);
  }

  // ---- encoder ----
  gemm_k<2, 1><<<dim3(256, 4), blk, 0, stream>>>(abuf, nullptr, enc_phi_W,
      enc_phi_b, nullptr, nullptr, e1, nullptr, 512, 512, 0);
  gemm_k<0, 1><<<dim3(256, 4), blk, 0, stream>>>(e1, nullptr, enc_phi_W + 262144,
      enc_phi_b + 512, nullptr, nullptr, e2, nullptr, 512, 512, 0);
  gemm_k<0, 9><<<dim3(256, 2), blk, 0, stream>>>(e2, nullptr, enc_mean_W,
      enc_mean_b, enc_std_W, enc_std_b, enc_mean, enc_std, 256, 512, 0);
  z0_k<<<4096, blk, 0, stream>>>(enc_mean, enc_std, eps, zk);
  flow_pre_k<<<16, 64, 0, stream>>>(pnf_u, pnf_w, uhat, wu);
  flow_k<<<8192, blk, 0, stream>>>(zk, pnf_w, pnf_b, uhat, wu, sldj);

  // ---- prior ----
  gemm_k<3, 1><<<dim3(256, 4), blk, 0, stream>>>(hbuf, nullptr, prior_phi_W,
      prior_phi_b, nullptr, nullptr, e1, nullptr, 512, 512, 0);
  gemm_k<0, 1><<<dim3(256, 4), blk, 0, stream>>>(e1, nullptr, prior_phi_W + 262144,
      prior_phi_b + 512, nullptr, nullptr, e2, nullptr, 512, 512, 0);
  gemm_k<0, 9><<<dim3(256, 2), blk, 0, stream>>>(e2, nullptr, prior_mean_W,
      prior_mean_b, prior_std_W, prior_std_b, prior_mean, prior_std, 256, 512, 0);

  // ---- decoder ----
  gemm_k<4, 1><<<dim3(256, 4), blk, 0, stream>>>(zk, hbuf, dec_W1, dec_b1,
      nullptr, nullptr, e1, nullptr, 512, 640, 0);
  gemm_k<0, 1><<<dim3(256, 4), blk, 0, stream>>>(e1, nullptr, dec_W2, dec_b2,
      nullptr, nullptr, e2, nullptr, 512, 512, 0);
  gemm_k<0, 9><<<dim3(256, 1), blk, 0, stream>>>(e2, nullptr, dec_mean_W,
      dec_mean_b, dec_std_W, dec_std_b, dec_mean, dec_std, 128, 512, 0);
}

// Round 2
// 814.847 us; speedup vs baseline: 3.8089x; 3.8089x over previous
//
#include <hip/hip_runtime.h>
#include <cstddef>
#include <cstdint>

#define DEVI __device__ __forceinline__

namespace {

typedef _Float16 f16;
typedef _Float16 half4 __attribute__((ext_vector_type(4)));
typedef _Float16 half8 __attribute__((ext_vector_type(8)));
typedef float floatx16 __attribute__((ext_vector_type(16)));

typedef const __attribute__((address_space(1))) void gvoid;
typedef __attribute__((address_space(3))) void lvoid;
#define GLL(gp, lp) __builtin_amdgcn_global_load_lds((gvoid*)(gp), (lvoid*)(lp), 16, 0, 0)

DEVI float sigmoidf_(float v) { return 1.f / (1.f + expf(-v)); }
DEVI float softplusf_(float v) { return fmaxf(v, 0.f) + log1pf(expf(-fabsf(v))); }

// ---------------------------------------------------------------------------
// fp32 -> fp16 conversion, table-driven (x, y, all weights in one launch)
// ---------------------------------------------------------------------------
struct CvtTab { const float* s[14]; f16* d[14]; int n4[14]; };

__global__ __launch_bounds__(256)
void cvt_k(CvtTab tab) {
  const int e = blockIdx.y;
  const int n4 = tab.n4[e];
  const float4* s = (const float4*)tab.s[e];
  f16* d = tab.d[e];
  for (int i = blockIdx.x * 256 + threadIdx.x; i < n4; i += gridDim.x * 256) {
    const float4 v = s[i];
    half4 o = {(f16)v.x, (f16)v.y, (f16)v.z, (f16)v.w};
    *(half4*)(d + (size_t)i * 4) = o;
  }
}

// ---------------------------------------------------------------------------
// fp16 MFMA GEMM: C[m,n] = act(sum_k A[m,k]*W[n,k] + bias[n])
// BM=128, BN=128, BK=64; 4 waves, each 64x64 = 2x2 frags of 32x32x16.
// LDS tiles [128 rows][8 chunks of 16B], chunk XOR-swizzled by (row&7).
// Staged via global_load_lds: per-lane GLOBAL addr pre-inverse-swizzled,
// LDS dest linear (wave-uniform base + lane*16).
// AM: 0 plain (lda)  1 REVCAT y(64)|h_n(512), K=576  2 CAT2 zk(128)|h_bt(512), K=640
// OM: 0 QRNN gates->f16 (tanh n<512, sigmoid else)  1 relu->f16  2 pair->f32 (sig|softplus @ Nh)
// ---------------------------------------------------------------------------
template <int AM, int OM>
__global__ __launch_bounds__(256)
void gemm16_k(const f16* __restrict__ A0, const f16* __restrict__ A1,
              const f16* __restrict__ W0, const f16* __restrict__ W1,
              const float* __restrict__ bias, const float* __restrict__ bias2,
              float* __restrict__ C, float* __restrict__ C2,
              f16* __restrict__ Ch, int N, int K, int lda) {
  __shared__ __align__(16) char lds[32768];
  char* ldsA = lds;
  char* ldsB = lds + 16384;
  const int tid = threadIdx.x;
  const int l = tid & 63, w = tid >> 6;
  const int m0 = blockIdx.x * 128, n0 = blockIdx.y * 128;
  const int Nh = N >> 1;

  // staging descriptors: 4 A-slots + 4 B-slots per lane (slot = 16B)
  const f16* pa[4];
  const f16* pa2[4];
  const f16* pb[4];
#pragma unroll
  for (int r = 0; r < 4; ++r) {
    const int s = w * 256 + r * 64 + l;
    const int row = s >> 3, c = s & 7;
    const int kc8 = (c ^ (row & 7)) * 8;        // inverse-swizzled logical k offset
    const int m = m0 + row;
    if constexpr (AM == 0) {
      pa[r] = A0 + (size_t)m * lda + kc8;
      pa2[r] = nullptr;
    } else if constexpr (AM == 1) {
      const int t = m >> 8, b = m & 255;
      const int mr = ((127 - t) << 8) | b;
      pa[r] = A0 + (size_t)mr * 64 + kc8;       // y part (step 0 only)
      pa2[r] = A1 + (size_t)mr * 512 + kc8;     // h part (steps >= 1)
    } else {
      pa[r] = A0 + (size_t)m * 128 + kc8;       // zk part (steps 0,1)
      pa2[r] = A1 + (size_t)m * 512 + kc8;      // h part (steps >= 2)
    }
    const int n = n0 + row;
    if constexpr (OM == 2) {
      pb[r] = (n < Nh ? W0 + (size_t)n * K : W1 + (size_t)(n - Nh) * K) + kc8;
    } else {
      pb[r] = W0 + (size_t)n * K + kc8;
    }
  }

  // fragment LDS byte offsets (fixed per lane)
  const int wr0 = (w >> 1) * 64, wc0 = (w & 1) * 64;
  int offA[2][4], offB[2][4];
#pragma unroll
  for (int mi = 0; mi < 2; ++mi) {
    const int row = wr0 + mi * 32 + (l & 31);
#pragma unroll
    for (int s16 = 0; s16 < 4; ++s16) {
      const int c = (s16 * 2 + (l >> 5)) ^ (row & 7);
      offA[mi][s16] = row * 128 + c * 16;
    }
  }
#pragma unroll
  for (int nj = 0; nj < 2; ++nj) {
    const int row = wc0 + nj * 32 + (l & 31);
#pragma unroll
    for (int s16 = 0; s16 < 4; ++s16) {
      const int c = (s16 * 2 + (l >> 5)) ^ (row & 7);
      offB[nj][s16] = row * 128 + c * 16;
    }
  }

  floatx16 acc[2][2] = {};
  const int nsteps = K >> 6;
  for (int st = 0; st < nsteps; ++st) {
#pragma unroll
    for (int r = 0; r < 4; ++r) {
      const f16* gp;
      if constexpr (AM == 0) {
        gp = pa[r] + st * 64;
      } else if constexpr (AM == 1) {
        gp = (st == 0) ? pa[r] : (pa2[r] + (st * 64 - 64));
      } else {
        gp = (st < 2) ? (pa[r] + st * 64) : (pa2[r] + (st * 64 - 128));
      }
      GLL(gp, ldsA + (size_t)(w * 256 + r * 64) * 16);
      GLL(pb[r] + st * 64, ldsB + (size_t)(w * 256 + r * 64) * 16);
    }
    __syncthreads();           // compiler drains vmcnt(0) before barrier
#pragma unroll
    for (int s16 = 0; s16 < 4; ++s16) {
      const half8 a0 = *(const half8*)(ldsA + offA[0][s16]);
      const half8 a1 = *(const half8*)(ldsA + offA[1][s16]);
      const half8 b0 = *(const half8*)(ldsB + offB[0][s16]);
      const half8 b1 = *(const half8*)(ldsB + offB[1][s16]);
      acc[0][0] = __builtin_amdgcn_mfma_f32_32x32x16_f16(a0, b0, acc[0][0], 0, 0, 0);
      acc[0][1] = __builtin_amdgcn_mfma_f32_32x32x16_f16(a0, b1, acc[0][1], 0, 0, 0);
      acc[1][0] = __builtin_amdgcn_mfma_f32_32x32x16_f16(a1, b0, acc[1][0], 0, 0, 0);
      acc[1][1] = __builtin_amdgcn_mfma_f32_32x32x16_f16(a1, b1, acc[1][1], 0, 0, 0);
    }
    __syncthreads();
  }

  // epilogue: C/D layout col = lane&31, row = (reg&3) + 8*(reg>>2) + 4*(lane>>5)
  const int col_l = l & 31;
#pragma unroll
  for (int nj = 0; nj < 2; ++nj) {
    const int gcol = n0 + wc0 + nj * 32 + col_l;
    if constexpr (OM == 2) {
      const bool second = gcol >= Nh;
      const float bv = second ? bias2[gcol - Nh] : bias[gcol];
      float* cp = second ? C2 : C;
      const int cl = second ? gcol - Nh : gcol;
#pragma unroll
      for (int mi = 0; mi < 2; ++mi) {
#pragma unroll
        for (int reg = 0; reg < 16; ++reg) {
          const int rl = (reg & 3) + 8 * (reg >> 2) + 4 * (l >> 5);
          const int grow = m0 + wr0 + mi * 32 + rl;
          const float v = acc[mi][nj][reg] + bv;
          cp[(size_t)grow * Nh + cl] = second ? softplusf_(v) : sigmoidf_(v);
        }
      }
    } else {
      const float bv = bias[gcol];
#pragma unroll
      for (int mi = 0; mi < 2; ++mi) {
#pragma unroll
        for (int reg = 0; reg < 16; ++reg) {
          const int rl = (reg & 3) + 8 * (reg >> 2) + 4 * (l >> 5);
          const int grow = m0 + wr0 + mi * 32 + rl;
          const float v = acc[mi][nj][reg] + bv;
          float rr;
          if constexpr (OM == 0) rr = (gcol < 512) ? tanhf(v) : sigmoidf_(v);
          else                   rr = fmaxf(v, 0.f);
          Ch[(size_t)grow * N + gcol] = (f16)rr;
        }
      }
    }
  }
}

// ---------------------------------------------------------------------------
// Forget-mult scan, full batch. Y: (t,b,1536) f16, gates pre-activated.
// MODE 0: write h natural (t,b,512) AND (b,t)-major copies.
// MODE 1: write arev[(b, 127-t)]-major only (encoder-ready layout).
// ---------------------------------------------------------------------------
typedef _Float16 f16x2 __attribute__((ext_vector_type(2)));

template <int MODE>
__global__ __launch_bounds__(256)
void scan_k(const f16* __restrict__ Y, f16* __restrict__ H1, f16* __restrict__ H2) {
  const int idx = blockIdx.x * 256 + threadIdx.x;   // 65536
  const int b = idx >> 8;
  const int h0 = (idx & 255) * 2;
  float c0 = 0.f, c1 = 0.f;
  for (int t = 0; t < 128; ++t) {
    const f16* p = Y + (size_t)(t * 256 + b) * 1536 + h0;
    const f16x2 zv = *(const f16x2*)(p);
    const f16x2 fv = *(const f16x2*)(p + 512);
    const f16x2 ov = *(const f16x2*)(p + 1024);
    const float f0 = (float)fv[0], f1 = (float)fv[1];
    c0 = f0 * (float)zv[0] + (1.f - f0) * c0;
    c1 = f1 * (float)zv[1] + (1.f - f1) * c1;
    f16x2 hv = {(f16)((float)ov[0] * c0), (f16)((float)ov[1] * c1)};
    if constexpr (MODE == 0) {
      *(f16x2*)(H1 + (size_t)(t * 256 + b) * 512 + h0) = hv;
      *(f16x2*)(H2 + (size_t)((b << 7) + t) * 512 + h0) = hv;
    } else {
      *(f16x2*)(H1 + (size_t)((b << 7) + (127 - t)) * 512 + h0) = hv;
    }
  }
}

// ---------------------------------------------------------------------------
__global__ __launch_bounds__(256)
void z0_k(const float* __restrict__ mean, const float* __restrict__ sd,
          const float* __restrict__ eps, float* __restrict__ z) {
  const int i = blockIdx.x * 256 + threadIdx.x;
  const float4 m = ((const float4*)mean)[i];
  const float4 s = ((const float4*)sd)[i];
  const float4 e = ((const float4*)eps)[i];
  ((float4*)z)[i] = make_float4(m.x + s.x * e.x, m.y + s.y * e.y,
                                m.z + s.z * e.z, m.w + s.w * e.w);
}

__global__ __launch_bounds__(64)
void flow_pre_k(const float* __restrict__ u, const float* __restrict__ w,
                float* __restrict__ uhat, float* __restrict__ wu) {
  const int k = blockIdx.x, l = threadIdx.x;
  const float w0 = w[k * 128 + l], w1 = w[k * 128 + 64 + l];
  const float u0 = u[k * 128 + l], u1 = u[k * 128 + 64 + l];
  float nrm = w0 * w0 + w1 * w1;
  float udw = u0 * w0 + u1 * w1;
#pragma unroll
  for (int o = 32; o; o >>= 1) { nrm += __shfl_xor(nrm, o); udw += __shfl_xor(udw, o); }
  const float inv = 1.f / sqrtf(nrm);
  const float coef = (softplusf_(udw) - 1.f) - udw;
  const float uh0 = coef * (w0 * inv) + u0;
  const float uh1 = coef * (w1 * inv) + u1;
  uhat[k * 128 + l] = uh0;
  uhat[k * 128 + 64 + l] = uh1;
  float dwu = w0 * uh0 + w1 * uh1;
#pragma unroll
  for (int o = 32; o; o >>= 1) dwu += __shfl_xor(dwu, o);
  if (l == 0) wu[k] = dwu;
}

__global__ __launch_bounds__(256)
void flow_k(float* __restrict__ z, const float* __restrict__ w,
            const float* __restrict__ b, const float* __restrict__ uhat,
            const float* __restrict__ wu, float* __restrict__ sldj,
            f16* __restrict__ zh) {
  const int row = blockIdx.x * 4 + (threadIdx.x >> 6);
  const int l = threadIdx.x & 63;
  float* zp = z + (size_t)row * 128;
  float z0 = zp[l], z1 = zp[64 + l];
  float sl = 0.f;
#pragma unroll
  for (int k = 0; k < 16; ++k) {
    const float w0 = w[k * 128 + l], w1 = w[k * 128 + 64 + l];
    float s = z0 * w0 + z1 * w1;
#pragma unroll
    for (int o = 32; o; o >>= 1) s += __shfl_xor(s, o);
    const float t = tanhf(s + b[k]);
    z0 += uhat[k * 128 + l] * t;
    z1 += uhat[k * 128 + 64 + l] * t;
    const float psi = (1.f - t * t) * wu[k];
    sl -= logf(fabsf(psi + 1.f) + 1e-8f);
  }
  zp[l] = z0;
  zp[64 + l] = z1;
  zh[(size_t)row * 128 + l] = (f16)z0;
  zh[(size_t)row * 128 + 64 + l] = (f16)z1;
  if (l == 0) sldj[row] = sl;
}

}  // namespace

extern "C" void kernel_launch(void* const* d_in, const int* in_sizes, int n_in,
                              void* d_out, int out_size, void* d_ws, size_t ws_size,
                              hipStream_t stream) {
  const float* x           = (const float*)d_in[0];
  const float* y           = (const float*)d_in[1];
  const float* eps         = (const float*)d_in[2];
  const float* hs_b        = (const float*)d_in[4];
  const float* q_b         = (const float*)d_in[6];
  const float* enc_phi_b   = (const float*)d_in[8];
  const float* enc_mean_b  = (const float*)d_in[10];
  const float* enc_std_b   = (const float*)d_in[12];
  const float* prior_phi_b = (const float*)d_in[14];
  const float* prior_mean_b= (const float*)d_in[16];
  const float* prior_std_b = (const float*)d_in[18];
  const float* dec_b1      = (const float*)d_in[20];
  const float* dec_b2      = (const float*)d_in[22];
  const float* dec_mean_b  = (const float*)d_in[24];
  const float* dec_std_b   = (const float*)d_in[26];
  const float* pnf_u       = (const float*)d_in[27];
  const float* pnf_w       = (const float*)d_in[28];
  const float* pnf_b       = (const float*)d_in[29];

  float* out = (float*)d_out;
  float* dec_mean  = out;
  float* dec_std   = out + 2097152;
  float* enc_mean  = out + 4194304;
  float* enc_std   = out + 8388608;
  float* prior_mean= out + 12582912;
  float* prior_std = out + 16777216;
  float* zk        = out + 20971520;
  float* sldj      = out + 25165824;

  // ---- workspace layout (bytes) ----
  char* ws = (char*)d_ws;
  f16* Ybuf  = (f16*)(ws + 0);             // (128,256,1536) f16 = 100.7 MB
  f16* e1    = (f16*)(ws + 0);             // alias (Y dead after scans)
  f16* e2    = (f16*)(ws + 33554432);
  f16* h_n   = (f16*)(ws + 100663296);     // h natural (t,b,512)
  f16* arev  = (f16*)(ws + 100663296);     // alias (h_n dead after inf gemm)
  f16* h_bt  = (f16*)(ws + 134217728);     // h (b,t)-major
  f16* zk_h  = (f16*)(ws + 167772160);     // zk f16 (b,t,128)
  f16* xh    = (f16*)(ws + 176160768);
  f16* yh    = (f16*)(ws + 180355072);
  f16* wbuf  = (f16*)(ws + 184549376);
  float* uhat= (float*)(ws + 190447616);
  float* wu  = (float*)(ws + 190455808);

  f16* w_hs   = wbuf + 0;        // 98304
  f16* w_q    = wbuf + 98304;    // 884736
  f16* w_ephi = wbuf + 983040;   // 524288 (2 layers)
  f16* w_emean= wbuf + 1507328;  // 65536
  f16* w_estd = wbuf + 1572864;
  f16* w_pphi = wbuf + 1638400;  // 524288
  f16* w_pmean= wbuf + 2162688;
  f16* w_pstd = wbuf + 2228224;
  f16* w_d1   = wbuf + 2293760;  // 327680
  f16* w_d2   = wbuf + 2621440;  // 262144
  f16* w_dmean= wbuf + 2883584;  // 32768
  f16* w_dstd = wbuf + 2916352;

  // ---- conversions: x, y, 12 weight tensors ----
  CvtTab tab;
  const float* srcs[14] = {x, y, (const float*)d_in[3], (const float*)d_in[5],
                           (const float*)d_in[7], (const float*)d_in[9],
                           (const float*)d_in[11], (const float*)d_in[13],
                           (const float*)d_in[15], (const float*)d_in[17],
                           (const float*)d_in[19], (const float*)d_in[21],
                           (const float*)d_in[23], (const float*)d_in[25]};
  f16* dsts[14] = {xh, yh, w_hs, w_q, w_ephi, w_emean, w_estd, w_pphi,
                   w_pmean, w_pstd, w_d1, w_d2, w_dmean, w_dstd};
  const int ns[14] = {2097152, 2097152, 98304, 884736, 524288, 65536, 65536,
                      524288, 65536, 65536, 327680, 262144, 32768, 32768};
  for (int i = 0; i < 14; ++i) { tab.s[i] = srcs[i]; tab.d[i] = dsts[i]; tab.n4[i] = ns[i] >> 2; }
  cvt_k<<<dim3(128, 14), 256, 0, stream>>>(tab);

  const dim3 blk(256);

  // ---- QRNN 1 (hidden-state): Y1 = gates(x @ hs_W^T) ----
  gemm16_k<0, 0><<<dim3(256, 12), blk, 0, stream>>>(xh, nullptr, w_hs, nullptr,
      hs_b, nullptr, nullptr, nullptr, Ybuf, 1536, 64, 64);
  scan_k<0><<<256, blk, 0, stream>>>(Ybuf, h_n, h_bt);

  // ---- QRNN 2 (inference, reversed [y,h]) ----
  gemm16_k<1, 0><<<dim3(256, 12), blk, 0, stream>>>(yh, h_n, w_q, nullptr,
      q_b, nullptr, nullptr, nullptr, Ybuf, 1536, 576, 0);
  scan_k<1><<<256, blk, 0, stream>>>(Ybuf, arev, nullptr);

  // ---- encoder ----
  gemm16_k<0, 1><<<dim3(256, 4), blk, 0, stream>>>(arev, nullptr, w_ephi, nullptr,
      enc_phi_b, nullptr, nullptr, nullptr, e1, 512, 512, 512);
  gemm16_k<0, 1><<<dim3(256, 4), blk, 0, stream>>>(e1, nullptr, w_ephi + 262144, nullptr,
      enc_phi_b + 512, nullptr, nullptr, nullptr, e2, 512, 512, 512);
  gemm16_k<0, 2><<<dim3(256, 2), blk, 0, stream>>>(e2, nullptr, w_emean, w_estd,
      enc_mean_b, enc_std_b, enc_mean, enc_std, nullptr, 256, 512, 512);
  z0_k<<<4096, blk, 0, stream>>>(enc_mean, enc_std, eps, zk);
  flow_pre_k<<<16, 64, 0, stream>>>(pnf_u, pnf_w, uhat, wu);
  flow_k<<<8192, blk, 0, stream>>>(zk, pnf_w, pnf_b, uhat, wu, sldj, zk_h);

  // ---- prior ----
  gemm16_k<0, 1><<<dim3(256, 4), blk, 0, stream>>>(h_bt, nullptr, w_pphi, nullptr,
      prior_phi_b, nullptr, nullptr, nullptr, e1, 512, 512, 512);
  gemm16_k<0, 1><<<dim3(256, 4), blk, 0, stream>>>(e1, nullptr, w_pphi + 262144, nullptr,
      prior_phi_b + 512, nullptr, nullptr, nullptr, e2, 512, 512, 512);
  gemm16_k<0, 2><<<dim3(256, 2), blk, 0, stream>>>(e2, nullptr, w_pmean, w_pstd,
      prior_mean_b, prior_std_b, prior_mean, prior_std, nullptr, 256, 512, 512);

  // ---- decoder ----
  gemm16_k<2, 1><<<dim3(256, 4), blk, 0, stream>>>(zk_h, h_bt, w_d1, nullptr,
      dec_b1, nullptr, nullptr, nullptr, e1, 512, 640, 0);
  gemm16_k<0, 1><<<dim3(256, 4), blk, 0, stream>>>(e1, nullptr, w_d2, nullptr,
      dec_b2, nullptr, nullptr, nullptr, e2, 512, 512, 512);
  gemm16_k<0, 2><<<dim3(256, 1), blk, 0, stream>>>(e2, nullptr, w_dmean, w_dstd,
      dec_mean_b, dec_std_b, dec_mean, dec_std, nullptr, 128, 512, 512);
}

// Round 6
// 657.288 us; speedup vs baseline: 4.7219x; 1.2397x over previous
//
#include <hip/hip_runtime.h>
#include <cstddef>
#include <cstdint>

#define DEVI __device__ __forceinline__

namespace {

typedef _Float16 f16;
typedef _Float16 half4 __attribute__((ext_vector_type(4)));
typedef _Float16 half8 __attribute__((ext_vector_type(8)));
typedef _Float16 f16x2 __attribute__((ext_vector_type(2)));
typedef float floatx16 __attribute__((ext_vector_type(16)));

typedef const __attribute__((address_space(1))) void gvoid;
typedef __attribute__((address_space(3))) void lvoid;
#define GLL(gp, lp) __builtin_amdgcn_global_load_lds((gvoid*)(gp), (lvoid*)(lp), 16, 0, 0)

constexpr float kLog2e = 1.4426950408889634f;
constexpr float kLn2   = 0.6931471805599453f;
DEVI float fexp2_(float x) { return __builtin_amdgcn_exp2f(x); }
DEVI float frcp_(float x)  { return __builtin_amdgcn_rcpf(x); }
DEVI float flog2_(float x) { return __builtin_amdgcn_logf(x); }
DEVI float fsig_(float v)  { return frcp_(1.f + fexp2_(-kLog2e * v)); }
DEVI float ftanh_(float v) { return 1.f - 2.f * frcp_(1.f + fexp2_(2.f * kLog2e * v)); }
DEVI float fsoftplus_(float v) {
  return fmaxf(v, 0.f) + kLn2 * flog2_(1.f + fexp2_(-kLog2e * fabsf(v)));
}

// ---------------------------------------------------------------------------
struct CvtTab { const float* s[14]; f16* d[14]; int n4[14]; };

__global__ __launch_bounds__(256)
void cvt_k(CvtTab tab) {
  const int e = blockIdx.y;
  const int n4 = tab.n4[e];
  const float4* s = (const float4*)tab.s[e];
  f16* d = tab.d[e];
  for (int i = blockIdx.x * 256 + threadIdx.x; i < n4; i += gridDim.x * 256) {
    const float4 v = s[i];
    half4 o = {(f16)v.x, (f16)v.y, (f16)v.z, (f16)v.w};
    *(half4*)(d + (size_t)i * 4) = o;
  }
}

// ---------------------------------------------------------------------------
// fp16 MFMA GEMM, double-buffered LDS + counted-vmcnt pipeline (T3 min-2ph).
// BM=BN=128, BK=64; 4 waves; 2x2 frags of 32x32x16 each.
// grid: x = N-tiles (so consecutive blocks share the A panel), y = M-tiles.
// AM: 0 plain(lda)  1 y(64)|h_bt reversed, K=576  2 zk(128)|h_bt, K=640
// OM: 0 QRNN gates->f16 (tanh n<512, sigm else)  1 relu->f16  2 pair->f32
// ---------------------------------------------------------------------------
template <int AM, int OM>
__global__ __launch_bounds__(256)
void gemm16_k(const f16* __restrict__ A0, const f16* __restrict__ A1,
              const f16* __restrict__ W0, const f16* __restrict__ W1,
              const float* __restrict__ bias, const float* __restrict__ bias2,
              float* __restrict__ C, float* __restrict__ C2,
              f16* __restrict__ Ch, int N, int K, int lda) {
  __shared__ __align__(16) char lds[65536];   // 2 x (A 16K + B 16K)
  const int tid = threadIdx.x;
  const int l = tid & 63, w = tid >> 6;
  const int m0 = blockIdx.y * 128, n0 = blockIdx.x * 128;
  const int Nh = N >> 1;

  // per-lane global staging pointers (16B slots, inverse-XOR-swizzled k)
  const f16* pa[4]; const f16* pa2[4]; const f16* pb[4];
#pragma unroll
  for (int r = 0; r < 4; ++r) {
    const int s = w * 256 + r * 64 + l;
    const int row = s >> 3, c = s & 7;
    const int kc8 = (c ^ (row & 7)) * 8;
    const int m = m0 + row;
    if constexpr (AM == 0) {
      pa[r] = A0 + (size_t)m * lda + kc8;
      pa2[r] = nullptr;
    } else if constexpr (AM == 1) {
      const int t = m >> 8, b = m & 255;
      pa[r]  = A0 + (size_t)((127 - t) * 256 + b) * 64 + kc8;      // y (flipped t)
      pa2[r] = A1 + (size_t)((b << 7) | (127 - t)) * 512 + kc8;    // h_bt (flipped t)
    } else {
      pa[r]  = A0 + (size_t)m * 128 + kc8;                          // zk_h
      pa2[r] = A1 + (size_t)m * 512 + kc8;                          // h_bt
    }
    const int n = n0 + row;
    if constexpr (OM == 2) {
      pb[r] = (n < Nh ? W0 + (size_t)n * K : W1 + (size_t)(n - Nh) * K) + kc8;
    } else {
      pb[r] = W0 + (size_t)n * K + kc8;
    }
  }

  // fragment LDS byte offsets
  const int wr0 = (w >> 1) * 64, wc0 = (w & 1) * 64;
  int offA[2][4], offB[2][4];
#pragma unroll
  for (int mi = 0; mi < 2; ++mi) {
    const int row = wr0 + mi * 32 + (l & 31);
#pragma unroll
    for (int s16 = 0; s16 < 4; ++s16) {
      const int c = (s16 * 2 + (l >> 5)) ^ (row & 7);
      offA[mi][s16] = row * 128 + c * 16;
    }
  }
#pragma unroll
  for (int nj = 0; nj < 2; ++nj) {
    const int row = wc0 + nj * 32 + (l & 31);
#pragma unroll
    for (int s16 = 0; s16 < 4; ++s16) {
      const int c = (s16 * 2 + (l >> 5)) ^ (row & 7);
      offB[nj][s16] = row * 128 + c * 16;
    }
  }

  // bias preload, forced complete BEFORE the pipeline (vmcnt bookkeeping)
  float bv[2];
#pragma unroll
  for (int nj = 0; nj < 2; ++nj) {
    const int gcol = n0 + wc0 + nj * 32 + (l & 31);
    if constexpr (OM == 2) {
      bv[nj] = (gcol >= Nh) ? bias2[gcol - Nh] : bias[gcol];
    } else {
      bv[nj] = bias[gcol];
    }
  }
  asm volatile("" : "+v"(bv[0]), "+v"(bv[1]));
  asm volatile("s_waitcnt vmcnt(0)" ::: "memory");

  auto stage = [&](int st, int buf) {
    char* dA = lds + buf * 32768;
    char* dB = dA + 16384;
#pragma unroll
    for (int r = 0; r < 4; ++r) {
      const f16* ga;
      if constexpr (AM == 0)      ga = pa[r] + st * 64;
      else if constexpr (AM == 1) ga = (st == 0) ? pa[r] : (pa2[r] + (st - 1) * 64);
      else                        ga = (st < 2) ? (pa[r] + st * 64) : (pa2[r] + (st - 2) * 64);
      GLL(ga, dA + (w * 256 + r * 64) * 16);
      GLL(pb[r] + st * 64, dB + (w * 256 + r * 64) * 16);
    }
  };

  floatx16 acc[2][2] = {};
  const int nsteps = K >> 6;
  stage(0, 0);
  for (int st = 0; st < nsteps; ++st) {
    const int cur = st & 1;
    if (st + 1 < nsteps) {
      stage(st + 1, cur ^ 1);                      // prefetch next K-step
      asm volatile("s_waitcnt vmcnt(8)" ::: "memory");  // cur buf landed
    } else {
      asm volatile("s_waitcnt vmcnt(0)" ::: "memory");
    }
    __builtin_amdgcn_s_barrier();                  // all waves: cur ready
    __builtin_amdgcn_sched_barrier(0);
    const char* cA = lds + cur * 32768;
    const char* cB = cA + 16384;
#pragma unroll
    for (int s16 = 0; s16 < 4; ++s16) {
      const half8 a0 = *(const half8*)(cA + offA[0][s16]);
      const half8 a1 = *(const half8*)(cA + offA[1][s16]);
      const half8 b0 = *(const half8*)(cB + offB[0][s16]);
      const half8 b1 = *(const half8*)(cB + offB[1][s16]);
      acc[0][0] = __builtin_amdgcn_mfma_f32_32x32x16_f16(a0, b0, acc[0][0], 0, 0, 0);
      acc[0][1] = __builtin_amdgcn_mfma_f32_32x32x16_f16(a0, b1, acc[0][1], 0, 0, 0);
      acc[1][0] = __builtin_amdgcn_mfma_f32_32x32x16_f16(a1, b0, acc[1][0], 0, 0, 0);
      acc[1][1] = __builtin_amdgcn_mfma_f32_32x32x16_f16(a1, b1, acc[1][1], 0, 0, 0);
    }
    __builtin_amdgcn_sched_barrier(0);
    asm volatile("s_waitcnt lgkmcnt(0)" ::: "memory");  // ds_reads done, vmcnt untouched
    __builtin_amdgcn_s_barrier();                  // cur may now be restaged
  }

  // epilogue: C/D layout col = lane&31, row = (reg&3) + 8*(reg>>2) + 4*(lane>>5)
  const int col_l = l & 31;
#pragma unroll
  for (int nj = 0; nj < 2; ++nj) {
    const int gcol = n0 + wc0 + nj * 32 + col_l;
    if constexpr (OM == 2) {
      const bool second = gcol >= Nh;
      float* cp = second ? C2 : C;
      const int cl = second ? gcol - Nh : gcol;
#pragma unroll
      for (int mi = 0; mi < 2; ++mi) {
#pragma unroll
        for (int reg = 0; reg < 16; ++reg) {
          const int rl = (reg & 3) + 8 * (reg >> 2) + 4 * (l >> 5);
          const int grow = m0 + wr0 + mi * 32 + rl;
          const float v = acc[mi][nj][reg] + bv[nj];
          cp[(size_t)grow * Nh + cl] = second ? fsoftplus_(v) : fsig_(v);
        }
      }
    } else {
#pragma unroll
      for (int mi = 0; mi < 2; ++mi) {
#pragma unroll
        for (int reg = 0; reg < 16; ++reg) {
          const int rl = (reg & 3) + 8 * (reg >> 2) + 4 * (l >> 5);
          const int grow = m0 + wr0 + mi * 32 + rl;
          const float v = acc[mi][nj][reg] + bv[nj];
          float rr;
          if constexpr (OM == 0) rr = (gcol < 512) ? ftanh_(v) : fsig_(v);
          else                   rr = fmaxf(v, 0.f);
          Ch[(size_t)grow * N + gcol] = (f16)rr;
        }
      }
    }
  }
}

// ---------------------------------------------------------------------------
// Forget-mult scan. Y: (t,b,1536) f16, gates pre-activated.
// MODE 0: write h_bt[(b<<7)|t].  MODE 1: write arev[(b<<7)|(127-t)].
// ---------------------------------------------------------------------------
template <int MODE>
__global__ __launch_bounds__(256)
void scan_k(const f16* __restrict__ Y, f16* __restrict__ H1) {
  const int idx = blockIdx.x * 256 + threadIdx.x;   // 65536
  const int b = idx >> 8;
  const int h0 = (idx & 255) * 2;
  float c0 = 0.f, c1 = 0.f;
  for (int t = 0; t < 128; ++t) {
    const f16* p = Y + (size_t)(t * 256 + b) * 1536 + h0;
    const f16x2 zv = *(const f16x2*)(p);
    const f16x2 fv = *(const f16x2*)(p + 512);
    const f16x2 ov = *(const f16x2*)(p + 1024);
    const float f0 = (float)fv[0], f1 = (float)fv[1];
    c0 = f0 * (float)zv[0] + (1.f - f0) * c0;
    c1 = f1 * (float)zv[1] + (1.f - f1) * c1;
    f16x2 hv = {(f16)((float)ov[0] * c0), (f16)((float)ov[1] * c1)};
    const int tt = (MODE == 0) ? t : (127 - t);
    *(f16x2*)(H1 + (size_t)((b << 7) | tt) * 512 + h0) = hv;
  }
}

// ---------------------------------------------------------------------------
__global__ __launch_bounds__(256)
void z0_k(const float* __restrict__ mean, const float* __restrict__ sd,
          const float* __restrict__ eps, float* __restrict__ z) {
  const int i = blockIdx.x * 256 + threadIdx.x;
  const float4 m = ((const float4*)mean)[i];
  const float4 s = ((const float4*)sd)[i];
  const float4 e = ((const float4*)eps)[i];
  ((float4*)z)[i] = make_float4(m.x + s.x * e.x, m.y + s.y * e.y,
                                m.z + s.z * e.z, m.w + s.w * e.w);
}

__global__ __launch_bounds__(64)
void flow_pre_k(const float* __restrict__ u, const float* __restrict__ w,
                float* __restrict__ uhat, float* __restrict__ wu) {
  const int k = blockIdx.x, l = threadIdx.x;
  const float w0 = w[k * 128 + l], w1 = w[k * 128 + 64 + l];
  const float u0 = u[k * 128 + l], u1 = u[k * 128 + 64 + l];
  float nrm = w0 * w0 + w1 * w1;
  float udw = u0 * w0 + u1 * w1;
#pragma unroll
  for (int o = 32; o; o >>= 1) { nrm += __shfl_xor(nrm, o); udw += __shfl_xor(udw, o); }
  const float inv = 1.f / sqrtf(nrm);
  const float coef = (fsoftplus_(udw) - 1.f) - udw;
  const float uh0 = coef * (w0 * inv) + u0;
  const float uh1 = coef * (w1 * inv) + u1;
  uhat[k * 128 + l] = uh0;
  uhat[k * 128 + 64 + l] = uh1;
  float dwu = w0 * uh0 + w1 * uh1;
#pragma unroll
  for (int o = 32; o; o >>= 1) dwu += __shfl_xor(dwu, o);
  if (l == 0) wu[k] = dwu;
}

__global__ __launch_bounds__(256)
void flow_k(float* __restrict__ z, const float* __restrict__ w,
            const float* __restrict__ b, const float* __restrict__ uhat,
            const float* __restrict__ wu, float* __restrict__ sldj,
            f16* __restrict__ zh) {
  const int row = blockIdx.x * 4 + (threadIdx.x >> 6);
  const int l = threadIdx.x & 63;
  float* zp = z + (size_t)row * 128;
  float z0 = zp[l], z1 = zp[64 + l];
  float sl = 0.f;
#pragma unroll
  for (int k = 0; k < 16; ++k) {
    const float w0 = w[k * 128 + l], w1 = w[k * 128 + 64 + l];
    float s = z0 * w0 + z1 * w1;
#pragma unroll
    for (int o = 32; o; o >>= 1) s += __shfl_xor(s, o);
    const float t = ftanh_(s + b[k]);
    z0 += uhat[k * 128 + l] * t;
    z1 += uhat[k * 128 + 64 + l] * t;
    const float psi = (1.f - t * t) * wu[k];
    sl -= kLn2 * flog2_(fabsf(psi + 1.f) + 1e-8f);
  }
  zp[l] = z0;
  zp[64 + l] = z1;
  zh[(size_t)row * 128 + l] = (f16)z0;
  zh[(size_t)row * 128 + 64 + l] = (f16)z1;
  if (l == 0) sldj[row] = sl;
}

}  // namespace

extern "C" void kernel_launch(void* const* d_in, const int* in_sizes, int n_in,
                              void* d_out, int out_size, void* d_ws, size_t ws_size,
                              hipStream_t stream) {
  const float* x           = (const float*)d_in[0];
  const float* y           = (const float*)d_in[1];
  const float* eps         = (const float*)d_in[2];
  const float* hs_b        = (const float*)d_in[4];
  const float* q_b         = (const float*)d_in[6];
  const float* enc_phi_b   = (const float*)d_in[8];
  const float* enc_mean_b  = (const float*)d_in[10];
  const float* enc_std_b   = (const float*)d_in[12];
  const float* prior_phi_b = (const float*)d_in[14];
  const float* prior_mean_b= (const float*)d_in[16];
  const float* prior_std_b = (const float*)d_in[18];
  const float* dec_b1      = (const float*)d_in[20];
  const float* dec_b2      = (const float*)d_in[22];
  const float* dec_mean_b  = (const float*)d_in[24];
  const float* dec_std_b   = (const float*)d_in[26];
  const float* pnf_u       = (const float*)d_in[27];
  const float* pnf_w       = (const float*)d_in[28];
  const float* pnf_b       = (const float*)d_in[29];

  float* out = (float*)d_out;
  float* dec_mean  = out;
  float* dec_std   = out + 2097152;
  float* enc_mean  = out + 4194304;
  float* enc_std   = out + 8388608;
  float* prior_mean= out + 12582912;
  float* prior_std = out + 16777216;
  float* zk        = out + 20971520;
  float* sldj      = out + 25165824;

  // ---- workspace layout (bytes) ----
  char* ws = (char*)d_ws;
  f16* Ybuf  = (f16*)(ws + 0);             // (128,256,1536) f16 = 100.7 MB
  f16* e1    = (f16*)(ws + 0);             // alias (Y dead after scans)
  f16* e2    = (f16*)(ws + 33554432);      // alias
  f16* arev  = (f16*)(ws + 100663296);
  f16* h_bt  = (f16*)(ws + 134217728);
  f16* zk_h  = (f16*)(ws + 167772160);
  f16* xh    = (f16*)(ws + 176160768);
  f16* yh    = (f16*)(ws + 180355072);
  f16* wbuf  = (f16*)(ws + 184549376);
  float* uhat= (float*)(ws + 190447616);
  float* wu  = (float*)(ws + 190455808);

  f16* w_hs   = wbuf + 0;
  f16* w_q    = wbuf + 98304;
  f16* w_ephi = wbuf + 983040;
  f16* w_emean= wbuf + 1507328;
  f16* w_estd = wbuf + 1572864;
  f16* w_pphi = wbuf + 1638400;
  f16* w_pmean= wbuf + 2162688;
  f16* w_pstd = wbuf + 2228224;
  f16* w_d1   = wbuf + 2293760;
  f16* w_d2   = wbuf + 2621440;
  f16* w_dmean= wbuf + 2883584;
  f16* w_dstd = wbuf + 2916352;

  CvtTab tab;
  const float* srcs[14] = {x, y, (const float*)d_in[3], (const float*)d_in[5],
                           (const float*)d_in[7], (const float*)d_in[9],
                           (const float*)d_in[11], (const float*)d_in[13],
                           (const float*)d_in[15], (const float*)d_in[17],
                           (const float*)d_in[19], (const float*)d_in[21],
                           (const float*)d_in[23], (const float*)d_in[25]};
  f16* dsts[14] = {xh, yh, w_hs, w_q, w_ephi, w_emean, w_estd, w_pphi,
                   w_pmean, w_pstd, w_d1, w_d2, w_dmean, w_dstd};
  const int ns[14] = {2097152, 2097152, 98304, 884736, 524288, 65536, 65536,
                      524288, 65536, 65536, 327680, 262144, 32768, 32768};
  for (int i = 0; i < 14; ++i) { tab.s[i] = srcs[i]; tab.d[i] = dsts[i]; tab.n4[i] = ns[i] >> 2; }
  cvt_k<<<dim3(128, 14), 256, 0, stream>>>(tab);

  const dim3 blk(256);

  // ---- QRNN 1 (hidden-state) ----
  gemm16_k<0, 0><<<dim3(12, 256), blk, 0, stream>>>(xh, nullptr, w_hs, nullptr,
      hs_b, nullptr, nullptr, nullptr, Ybuf, 1536, 64, 64);
  scan_k<0><<<256, blk, 0, stream>>>(Ybuf, h_bt);

  // ---- QRNN 2 (inference, reversed [y,h]) ----
  gemm16_k<1, 0><<<dim3(12, 256), blk, 0, stream>>>(yh, h_bt, w_q, nullptr,
      q_b, nullptr, nullptr, nullptr, Ybuf, 1536, 576, 0);
  scan_k<1><<<256, blk, 0, stream>>>(Ybuf, arev);

  // ---- encoder ----
  gemm16_k<0, 1><<<dim3(4, 256), blk, 0, stream>>>(arev, nullptr, w_ephi, nullptr,
      enc_phi_b, nullptr, nullptr, nullptr, e1, 512, 512, 512);
  gemm16_k<0, 1><<<dim3(4, 256), blk, 0, stream>>>(e1, nullptr, w_ephi + 262144, nullptr,
      enc_phi_b + 512, nullptr, nullptr, nullptr, e2, 512, 512, 512);
  gemm16_k<0, 2><<<dim3(2, 256), blk, 0, stream>>>(e2, nullptr, w_emean, w_estd,
      enc_mean_b, enc_std_b, enc_mean, enc_std, nullptr, 256, 512, 512);
  z0_k<<<4096, blk, 0, stream>>>(enc_mean, enc_std, eps, zk);
  flow_pre_k<<<16, 64, 0, stream>>>(pnf_u, pnf_w, uhat, wu);
  flow_k<<<8192, blk, 0, stream>>>(zk, pnf_w, pnf_b, uhat, wu, sldj, zk_h);

  // ---- prior ----
  gemm16_k<0, 1><<<dim3(4, 256), blk, 0, stream>>>(h_bt, nullptr, w_pphi, nullptr,
      prior_phi_b, nullptr, nullptr, nullptr, e1, 512, 512, 512);
  gemm16_k<0, 1><<<dim3(4, 256), blk, 0, stream>>>(e1, nullptr, w_pphi + 262144, nullptr,
      prior_phi_b + 512, nullptr, nullptr, nullptr, e2, 512, 512, 512);
  gemm16_k<0, 2><<<dim3(2, 256), blk, 0, stream>>>(e2, nullptr, w_pmean, w_pstd,
      prior_mean_b, prior_std_b, prior_mean, prior_std, nullptr, 256, 512, 512);

  // ---- decoder ----
  gemm16_k<2, 1><<<dim3(4, 256), blk, 0, stream>>>(zk_h, h_bt, w_d1, nullptr,
      dec_b1, nullptr, nullptr, nullptr, e1, 512, 640, 0);
  gemm16_k<0, 1><<<dim3(4, 256), blk, 0, stream>>>(e1, nullptr, w_d2, nullptr,
      dec_b2, nullptr, nullptr, nullptr, e2, 512, 512, 512);
  gemm16_k<0, 2><<<dim3(1, 256), blk, 0, stream>>>(e2, nullptr, w_dmean, w_dstd,
      dec_mean_b, dec_std_b, dec_mean, dec_std, nullptr, 128, 512, 512);
}

// Round 7
// 649.282 us; speedup vs baseline: 4.7801x; 1.0123x over previous
//
#include <hip/hip_runtime.h>
#include <cstddef>
#include <cstdint>

#define DEVI __device__ __forceinline__

namespace {

typedef _Float16 f16;
typedef _Float16 half4 __attribute__((ext_vector_type(4)));
typedef _Float16 half8 __attribute__((ext_vector_type(8)));
typedef _Float16 f16x2 __attribute__((ext_vector_type(2)));
typedef float floatx16 __attribute__((ext_vector_type(16)));

typedef const __attribute__((address_space(1))) void gvoid;
typedef __attribute__((address_space(3))) void lvoid;
#define GLL(gp, lp) __builtin_amdgcn_global_load_lds((gvoid*)(gp), (lvoid*)(lp), 16, 0, 0)

constexpr float kLog2e = 1.4426950408889634f;
constexpr float kLn2   = 0.6931471805599453f;
DEVI float fexp2_(float x) { return __builtin_amdgcn_exp2f(x); }
DEVI float frcp_(float x)  { return __builtin_amdgcn_rcpf(x); }
DEVI float flog2_(float x) { return __builtin_amdgcn_logf(x); }
DEVI float fsig_(float v)  { return frcp_(1.f + fexp2_(-kLog2e * v)); }
DEVI float ftanh_(float v) { return 1.f - 2.f * frcp_(1.f + fexp2_(2.f * kLog2e * v)); }
DEVI float fsoftplus_(float v) {
  return fmaxf(v, 0.f) + kLn2 * flog2_(1.f + fexp2_(-kLog2e * fabsf(v)));
}

// ---------------------------------------------------------------------------
struct CvtTab { const float* s[14]; f16* d[14]; int n4[14]; };

__global__ __launch_bounds__(256)
void cvt_k(CvtTab tab) {
  const int e = blockIdx.y;
  const int n4 = tab.n4[e];
  const float4* s = (const float4*)tab.s[e];
  f16* d = tab.d[e];
  for (int i = blockIdx.x * 256 + threadIdx.x; i < n4; i += gridDim.x * 256) {
    const float4 v = s[i];
    half4 o = {(f16)v.x, (f16)v.y, (f16)v.z, (f16)v.w};
    *(half4*)(d + (size_t)i * 4) = o;
  }
}

// ---------------------------------------------------------------------------
// fp16 MFMA GEMM: BM=BN=256, BK=64; 512 threads = 8 waves (2x4), wave-tile
// 128x64 = 4x2 frags of 32x32x16. LDS 2 x (A 32K + B 32K) = 128KB, XOR-swz.
// Double-buffered counted-vmcnt pipeline (validated R6 scheme, 8 loads/wave).
// Bijective XCD swizzle on blockIdx (all grids divisible by 8); logical id is
// m-major so the ntx blocks sharing an A-panel land on the same XCD's L2.
// AM: 0 plain(lda)  1 y(64)|h_bt reversed, K=576  2 zk(128)|h_bt, K=640
// OM: 0 QRNN gates->f16 (tanh n<512, sigm else)  1 relu->f16  2 pair->f32
// ---------------------------------------------------------------------------
template <int AM, int OM>
__global__ __launch_bounds__(512, 2)
void gemm16_k(const f16* __restrict__ A0, const f16* __restrict__ A1,
              const f16* __restrict__ W0, const f16* __restrict__ W1,
              const float* __restrict__ bias, const float* __restrict__ bias2,
              float* __restrict__ C, float* __restrict__ C2,
              f16* __restrict__ Ch, int N, int K, int lda, int ntx) {
  __shared__ __align__(16) char lds[131072];
  const int tid = threadIdx.x;
  const int l = tid & 63, w = tid >> 6;
  const int nwg = gridDim.x;
  int bid = blockIdx.x;
  bid = (bid & 7) * (nwg >> 3) + (bid >> 3);     // XCD-contiguous logical ids
  const int m0 = (bid / ntx) * 256;
  const int n0 = (bid % ntx) * 256;
  const int Nh = N >> 1;

  // staging: A = 2048 slots of 16B (256 rows x 8 chunks), B = 2048 slots.
  // thread covers slot r*512+tid for r=0..3 in each of A and B.
  const f16* pa[4]; const f16* pa2[4]; const f16* pb[4];
#pragma unroll
  for (int r = 0; r < 4; ++r) {
    const int s = r * 512 + tid;
    const int row = s >> 3, c = s & 7;
    const int kc8 = (c ^ (row & 7)) * 8;         // inverse-swizzled k offset
    const int m = m0 + row;
    if constexpr (AM == 0) {
      pa[r] = A0 + (size_t)m * lda + kc8;
      pa2[r] = nullptr;
    } else if constexpr (AM == 1) {
      const int t = m >> 8, b = m & 255;
      pa[r]  = A0 + (size_t)((127 - t) * 256 + b) * 64 + kc8;    // y (flip t)
      pa2[r] = A1 + (size_t)((b << 7) | (127 - t)) * 512 + kc8;  // h_bt (flip t)
    } else {
      pa[r]  = A0 + (size_t)m * 128 + kc8;                        // zk_h
      pa2[r] = A1 + (size_t)m * 512 + kc8;                        // h_bt
    }
    int n = n0 + row;
    if constexpr (OM == 2) n = n < N ? n : N - 1;                 // N=128 clamp
    if constexpr (OM == 2) {
      pb[r] = (n < Nh ? W0 + (size_t)n * K : W1 + (size_t)(n - Nh) * K) + kc8;
    } else {
      pb[r] = W0 + (size_t)n * K + kc8;
    }
  }

  // fragment LDS byte offsets: wave (wr,wc) of 2x4; rows*128 + swz-chunk*16
  const int wr = w >> 2, wc = w & 3;
  int offA[4][4], offB[2][4];
#pragma unroll
  for (int mi = 0; mi < 4; ++mi) {
    const int row = wr * 128 + mi * 32 + (l & 31);
#pragma unroll
    for (int s16 = 0; s16 < 4; ++s16) {
      const int c = (s16 * 2 + (l >> 5)) ^ (row & 7);
      offA[mi][s16] = row * 128 + c * 16;
    }
  }
#pragma unroll
  for (int nj = 0; nj < 2; ++nj) {
    const int row = wc * 64 + nj * 32 + (l & 31);
#pragma unroll
    for (int s16 = 0; s16 < 4; ++s16) {
      const int c = (s16 * 2 + (l >> 5)) ^ (row & 7);
      offB[nj][s16] = row * 128 + c * 16;
    }
  }

  // bias preload, drained BEFORE the pipeline (keeps vmcnt ledger exact)
  float bv[2];
#pragma unroll
  for (int nj = 0; nj < 2; ++nj) {
    int gcol = n0 + wc * 64 + nj * 32 + (l & 31);
    if constexpr (OM == 2) {
      const int gi = gcol < N ? gcol : N - 1;
      bv[nj] = (gi >= Nh) ? bias2[gi - Nh] : bias[gi];
    } else {
      bv[nj] = bias[gcol];
    }
  }
  asm volatile("" : "+v"(bv[0]), "+v"(bv[1]));
  asm volatile("s_waitcnt vmcnt(0)" ::: "memory");

  auto stage = [&](int st, int buf) {
    char* dA = lds + buf * 65536;
    char* dB = dA + 32768;
#pragma unroll
    for (int r = 0; r < 4; ++r) {
      const f16* ga;
      if constexpr (AM == 0)      ga = pa[r] + st * 64;
      else if constexpr (AM == 1) ga = (st == 0) ? pa[r] : (pa2[r] + (st - 1) * 64);
      else                        ga = (st < 2) ? (pa[r] + st * 64) : (pa2[r] + (st - 2) * 64);
      GLL(ga, dA + (r * 512 + w * 64) * 16);               // wave-uniform base
      GLL(pb[r] + st * 64, dB + (r * 512 + w * 64) * 16);
    }
  };

  floatx16 acc[4][2] = {};
  const int nsteps = K >> 6;
  stage(0, 0);
  for (int st = 0; st < nsteps; ++st) {
    const int cur = st & 1;
    if (st + 1 < nsteps) {
      stage(st + 1, cur ^ 1);                              // prefetch next
      asm volatile("s_waitcnt vmcnt(8)" ::: "memory");     // cur landed
    } else {
      asm volatile("s_waitcnt vmcnt(0)" ::: "memory");
    }
    __builtin_amdgcn_s_barrier();
    __builtin_amdgcn_sched_barrier(0);
    const char* cA = lds + cur * 65536;
    const char* cB = cA + 32768;
#pragma unroll
    for (int s16 = 0; s16 < 4; ++s16) {
      half8 a0 = *(const half8*)(cA + offA[0][s16]);
      half8 a1 = *(const half8*)(cA + offA[1][s16]);
      half8 a2 = *(const half8*)(cA + offA[2][s16]);
      half8 a3 = *(const half8*)(cA + offA[3][s16]);
      half8 b0 = *(const half8*)(cB + offB[0][s16]);
      half8 b1 = *(const half8*)(cB + offB[1][s16]);
      acc[0][0] = __builtin_amdgcn_mfma_f32_32x32x16_f16(a0, b0, acc[0][0], 0, 0, 0);
      acc[0][1] = __builtin_amdgcn_mfma_f32_32x32x16_f16(a0, b1, acc[0][1], 0, 0, 0);
      acc[1][0] = __builtin_amdgcn_mfma_f32_32x32x16_f16(a1, b0, acc[1][0], 0, 0, 0);
      acc[1][1] = __builtin_amdgcn_mfma_f32_32x32x16_f16(a1, b1, acc[1][1], 0, 0, 0);
      acc[2][0] = __builtin_amdgcn_mfma_f32_32x32x16_f16(a2, b0, acc[2][0], 0, 0, 0);
      acc[2][1] = __builtin_amdgcn_mfma_f32_32x32x16_f16(a2, b1, acc[2][1], 0, 0, 0);
      acc[3][0] = __builtin_amdgcn_mfma_f32_32x32x16_f16(a3, b0, acc[3][0], 0, 0, 0);
      acc[3][1] = __builtin_amdgcn_mfma_f32_32x32x16_f16(a3, b1, acc[3][1], 0, 0, 0);
    }
    __builtin_amdgcn_sched_barrier(0);
    asm volatile("s_waitcnt lgkmcnt(0)" ::: "memory");
    __builtin_amdgcn_s_barrier();
  }

  // epilogue: C/D col = lane&31, row = (reg&3) + 8*(reg>>2) + 4*(lane>>5)
  const int col_l = l & 31;
  const int hi4 = (l >> 5) * 4;
#pragma unroll
  for (int nj = 0; nj < 2; ++nj) {
    const int gcol = n0 + wc * 64 + nj * 32 + col_l;
    if constexpr (OM == 2) {
      if (gcol < N) {
        const bool second = gcol >= Nh;
        float* cp = second ? C2 : C;
        const int cl = second ? gcol - Nh : gcol;
#pragma unroll
        for (int mi = 0; mi < 4; ++mi) {
#pragma unroll
          for (int reg = 0; reg < 16; ++reg) {
            const int rl = (reg & 3) + 8 * (reg >> 2) + hi4;
            const int grow = m0 + wr * 128 + mi * 32 + rl;
            const float v = acc[mi][nj][reg] + bv[nj];
            cp[(size_t)grow * Nh + cl] = second ? fsoftplus_(v) : fsig_(v);
          }
        }
      }
    } else {
#pragma unroll
      for (int mi = 0; mi < 4; ++mi) {
#pragma unroll
        for (int reg = 0; reg < 16; ++reg) {
          const int rl = (reg & 3) + 8 * (reg >> 2) + hi4;
          const int grow = m0 + wr * 128 + mi * 32 + rl;
          const float v = acc[mi][nj][reg] + bv[nj];
          float rr;
          if constexpr (OM == 0) rr = (gcol < 512) ? ftanh_(v) : fsig_(v);
          else                   rr = fmaxf(v, 0.f);
          Ch[(size_t)grow * N + gcol] = (f16)rr;
        }
      }
    }
  }
}

// ---------------------------------------------------------------------------
// Forget-mult scan. Y: (t,b,1536) f16, gates pre-activated.
// MODE 0: write h_bt[(b<<7)|t].  MODE 1: write arev[(b<<7)|(127-t)].
// ---------------------------------------------------------------------------
template <int MODE>
__global__ __launch_bounds__(256)
void scan_k(const f16* __restrict__ Y, f16* __restrict__ H1) {
  const int idx = blockIdx.x * 256 + threadIdx.x;   // 65536
  const int b = idx >> 8;
  const int h0 = (idx & 255) * 2;
  float c0 = 0.f, c1 = 0.f;
  for (int t = 0; t < 128; ++t) {
    const f16* p = Y + (size_t)(t * 256 + b) * 1536 + h0;
    const f16x2 zv = *(const f16x2*)(p);
    const f16x2 fv = *(const f16x2*)(p + 512);
    const f16x2 ov = *(const f16x2*)(p + 1024);
    const float f0 = (float)fv[0], f1 = (float)fv[1];
    c0 = f0 * (float)zv[0] + (1.f - f0) * c0;
    c1 = f1 * (float)zv[1] + (1.f - f1) * c1;
    f16x2 hv = {(f16)((float)ov[0] * c0), (f16)((float)ov[1] * c1)};
    const int tt = (MODE == 0) ? t : (127 - t);
    *(f16x2*)(H1 + (size_t)((b << 7) | tt) * 512 + h0) = hv;
  }
}

// ---------------------------------------------------------------------------
__global__ __launch_bounds__(256)
void z0_k(const float* __restrict__ mean, const float* __restrict__ sd,
          const float* __restrict__ eps, float* __restrict__ z) {
  const int i = blockIdx.x * 256 + threadIdx.x;
  const float4 m = ((const float4*)mean)[i];
  const float4 s = ((const float4*)sd)[i];
  const float4 e = ((const float4*)eps)[i];
  ((float4*)z)[i] = make_float4(m.x + s.x * e.x, m.y + s.y * e.y,
                                m.z + s.z * e.z, m.w + s.w * e.w);
}

__global__ __launch_bounds__(64)
void flow_pre_k(const float* __restrict__ u, const float* __restrict__ w,
                float* __restrict__ uhat, float* __restrict__ wu) {
  const int k = blockIdx.x, l = threadIdx.x;
  const float w0 = w[k * 128 + l], w1 = w[k * 128 + 64 + l];
  const float u0 = u[k * 128 + l], u1 = u[k * 128 + 64 + l];
  float nrm = w0 * w0 + w1 * w1;
  float udw = u0 * w0 + u1 * w1;
#pragma unroll
  for (int o = 32; o; o >>= 1) { nrm += __shfl_xor(nrm, o); udw += __shfl_xor(udw, o); }
  const float inv = 1.f / sqrtf(nrm);
  const float coef = (fsoftplus_(udw) - 1.f) - udw;
  const float uh0 = coef * (w0 * inv) + u0;
  const float uh1 = coef * (w1 * inv) + u1;
  uhat[k * 128 + l] = uh0;
  uhat[k * 128 + 64 + l] = uh1;
  float dwu = w0 * uh0 + w1 * uh1;
#pragma unroll
  for (int o = 32; o; o >>= 1) dwu += __shfl_xor(dwu, o);
  if (l == 0) wu[k] = dwu;
}

__global__ __launch_bounds__(256)
void flow_k(float* __restrict__ z, const float* __restrict__ w,
            const float* __restrict__ b, const float* __restrict__ uhat,
            const float* __restrict__ wu, float* __restrict__ sldj,
            f16* __restrict__ zh) {
  const int row = blockIdx.x * 4 + (threadIdx.x >> 6);
  const int l = threadIdx.x & 63;
  float* zp = z + (size_t)row * 128;
  float z0 = zp[l], z1 = zp[64 + l];
  float sl = 0.f;
#pragma unroll
  for (int k = 0; k < 16; ++k) {
    const float w0 = w[k * 128 + l], w1 = w[k * 128 + 64 + l];
    float s = z0 * w0 + z1 * w1;
#pragma unroll
    for (int o = 32; o; o >>= 1) s += __shfl_xor(s, o);
    const float t = ftanh_(s + b[k]);
    z0 += uhat[k * 128 + l] * t;
    z1 += uhat[k * 128 + 64 + l] * t;
    const float psi = (1.f - t * t) * wu[k];
    sl -= kLn2 * flog2_(fabsf(psi + 1.f) + 1e-8f);
  }
  zp[l] = z0;
  zp[64 + l] = z1;
  zh[(size_t)row * 128 + l] = (f16)z0;
  zh[(size_t)row * 128 + 64 + l] = (f16)z1;
  if (l == 0) sldj[row] = sl;
}

}  // namespace

extern "C" void kernel_launch(void* const* d_in, const int* in_sizes, int n_in,
                              void* d_out, int out_size, void* d_ws, size_t ws_size,
                              hipStream_t stream) {
  const float* x           = (const float*)d_in[0];
  const float* y           = (const float*)d_in[1];
  const float* eps         = (const float*)d_in[2];
  const float* hs_b        = (const float*)d_in[4];
  const float* q_b         = (const float*)d_in[6];
  const float* enc_phi_b   = (const float*)d_in[8];
  const float* enc_mean_b  = (const float*)d_in[10];
  const float* enc_std_b   = (const float*)d_in[12];
  const float* prior_phi_b = (const float*)d_in[14];
  const float* prior_mean_b= (const float*)d_in[16];
  const float* prior_std_b = (const float*)d_in[18];
  const float* dec_b1      = (const float*)d_in[20];
  const float* dec_b2      = (const float*)d_in[22];
  const float* dec_mean_b  = (const float*)d_in[24];
  const float* dec_std_b   = (const float*)d_in[26];
  const float* pnf_u       = (const float*)d_in[27];
  const float* pnf_w       = (const float*)d_in[28];
  const float* pnf_b       = (const float*)d_in[29];

  float* out = (float*)d_out;
  float* dec_mean  = out;
  float* dec_std   = out + 2097152;
  float* enc_mean  = out + 4194304;
  float* enc_std   = out + 8388608;
  float* prior_mean= out + 12582912;
  float* prior_std = out + 16777216;
  float* zk        = out + 20971520;
  float* sldj      = out + 25165824;

  // ---- workspace layout (bytes) ----
  char* ws = (char*)d_ws;
  f16* Ybuf  = (f16*)(ws + 0);             // (128,256,1536) f16 = 100.7 MB
  f16* e1    = (f16*)(ws + 0);             // alias (Y dead after scans)
  f16* e2    = (f16*)(ws + 33554432);      // alias
  f16* arev  = (f16*)(ws + 100663296);
  f16* h_bt  = (f16*)(ws + 134217728);
  f16* zk_h  = (f16*)(ws + 167772160);
  f16* xh    = (f16*)(ws + 176160768);
  f16* yh    = (f16*)(ws + 180355072);
  f16* wbuf  = (f16*)(ws + 184549376);
  float* uhat= (float*)(ws + 190447616);
  float* wu  = (float*)(ws + 190455808);

  f16* w_hs   = wbuf + 0;
  f16* w_q    = wbuf + 98304;
  f16* w_ephi = wbuf + 983040;
  f16* w_emean= wbuf + 1507328;
  f16* w_estd = wbuf + 1572864;
  f16* w_pphi = wbuf + 1638400;
  f16* w_pmean= wbuf + 2162688;
  f16* w_pstd = wbuf + 2228224;
  f16* w_d1   = wbuf + 2293760;
  f16* w_d2   = wbuf + 2621440;
  f16* w_dmean= wbuf + 2883584;
  f16* w_dstd = wbuf + 2916352;

  CvtTab tab;
  const float* srcs[14] = {x, y, (const float*)d_in[3], (const float*)d_in[5],
                           (const float*)d_in[7], (const float*)d_in[9],
                           (const float*)d_in[11], (const float*)d_in[13],
                           (const float*)d_in[15], (const float*)d_in[17],
                           (const float*)d_in[19], (const float*)d_in[21],
                           (const float*)d_in[23], (const float*)d_in[25]};
  f16* dsts[14] = {xh, yh, w_hs, w_q, w_ephi, w_emean, w_estd, w_pphi,
                   w_pmean, w_pstd, w_d1, w_d2, w_dmean, w_dstd};
  const int ns[14] = {2097152, 2097152, 98304, 884736, 524288, 65536, 65536,
                      524288, 65536, 65536, 327680, 262144, 32768, 32768};
  for (int i = 0; i < 14; ++i) { tab.s[i] = srcs[i]; tab.d[i] = dsts[i]; tab.n4[i] = ns[i] >> 2; }
  cvt_k<<<dim3(128, 14), 256, 0, stream>>>(tab);

  const dim3 blk(512);

  // ---- QRNN 1 (hidden-state): N=1536, K=64, ntx=6 -> 768 blocks ----
  gemm16_k<0, 0><<<768, blk, 0, stream>>>(xh, nullptr, w_hs, nullptr,
      hs_b, nullptr, nullptr, nullptr, Ybuf, 1536, 64, 64, 6);
  scan_k<0><<<256, 256, 0, stream>>>(Ybuf, h_bt);

  // ---- QRNN 2 (inference, reversed [y,h]): K=576 ----
  gemm16_k<1, 0><<<768, blk, 0, stream>>>(yh, h_bt, w_q, nullptr,
      q_b, nullptr, nullptr, nullptr, Ybuf, 1536, 576, 0, 6);
  scan_k<1><<<256, 256, 0, stream>>>(Ybuf, arev);

  // ---- encoder ----
  gemm16_k<0, 1><<<256, blk, 0, stream>>>(arev, nullptr, w_ephi, nullptr,
      enc_phi_b, nullptr, nullptr, nullptr, e1, 512, 512, 512, 2);
  gemm16_k<0, 1><<<256, blk, 0, stream>>>(e1, nullptr, w_ephi + 262144, nullptr,
      enc_phi_b + 512, nullptr, nullptr, nullptr, e2, 512, 512, 512, 2);
  gemm16_k<0, 2><<<128, blk, 0, stream>>>(e2, nullptr, w_emean, w_estd,
      enc_mean_b, enc_std_b, enc_mean, enc_std, nullptr, 256, 512, 512, 1);
  z0_k<<<4096, 256, 0, stream>>>(enc_mean, enc_std, eps, zk);
  flow_pre_k<<<16, 64, 0, stream>>>(pnf_u, pnf_w, uhat, wu);
  flow_k<<<8192, 256, 0, stream>>>(zk, pnf_w, pnf_b, uhat, wu, sldj, zk_h);

  // ---- prior ----
  gemm16_k<0, 1><<<256, blk, 0, stream>>>(h_bt, nullptr, w_pphi, nullptr,
      prior_phi_b, nullptr, nullptr, nullptr, e1, 512, 512, 512, 2);
  gemm16_k<0, 1><<<256, blk, 0, stream>>>(e1, nullptr, w_pphi + 262144, nullptr,
      prior_phi_b + 512, nullptr, nullptr, nullptr, e2, 512, 512, 512, 2);
  gemm16_k<0, 2><<<128, blk, 0, stream>>>(e2, nullptr, w_pmean, w_pstd,
      prior_mean_b, prior_std_b, prior_mean, prior_std, nullptr, 256, 512, 512, 1);

  // ---- decoder ----
  gemm16_k<2, 1><<<256, blk, 0, stream>>>(zk_h, h_bt, w_d1, nullptr,
      dec_b1, nullptr, nullptr, nullptr, e1, 512, 640, 0, 2);
  gemm16_k<0, 1><<<256, blk, 0, stream>>>(e1, nullptr, w_d2, nullptr,
      dec_b2, nullptr, nullptr, nullptr, e2, 512, 512, 512, 2);
  gemm16_k<0, 2><<<128, blk, 0, stream>>>(e2, nullptr, w_dmean, w_dstd,
      dec_mean_b, dec_std_b, dec_mean, dec_std, nullptr, 128, 512, 512, 1);
}